// Round 3
// baseline (130.431 us; speedup 1.0000x reference)
//
#include <hip/hip_runtime.h>

#define IN_CH 96
#define OUT_CH 384
#define TILE 32          // rows of x staged in LDS per iteration
#define LDS_STRIDE 100   // pad 96->100 floats (+4 banks/row skew, keeps 16B align)
#define THREADS 384

typedef float f32x4 __attribute__((ext_vector_type(4)));  // native vec for nontemporal builtins

// Thread t computes 4 consecutive output channels (one joint's quarter) for
// rows rl, rl+4, rl+8, ... of the current 32-row tile.
//   cg   = t % 96  -> channel group (4 channels each)
//   rl   = t / 96  -> row lane 0..3
// All 4 channels of a group share the SAME contiguous 12-float x-slice
// (c0 = clamp(joint-1,0,21)*4; mask zeroes the dead edges for joints 0/23),
// so the inner loop is 3x ds_read_b128 + 48 FMA + one float4 store.
__global__ __launch_bounds__(THREADS, 5) void skel_linear_kernel(
    const float* __restrict__ x,
    const float* __restrict__ weight,
    const float* __restrict__ mask,
    const float* __restrict__ bias,
    float* __restrict__ out,
    int batch)
{
    const int t     = threadIdx.x;
    const int cg    = t % 96;
    const int rl    = t / 96;
    const int chan  = cg * 4;
    const int joint = cg >> 2;
    const int jc    = (joint - 1 < 0) ? 0 : ((joint - 1 > 21) ? 21 : joint - 1);
    const int c0    = jc * 4;

    // Hoist masked weights + bias into registers (once per launch).
    float w[4][12];
    float b[4];
#pragma unroll
    for (int j = 0; j < 4; ++j) {
        const size_t row = (size_t)(chan + j) * IN_CH;
#pragma unroll
        for (int c = 0; c < 12; ++c)
            w[j][c] = weight[row + c0 + c] * mask[row + c0 + c];
        b[j] = bias[chan + j];
    }

    __shared__ float xs[TILE * LDS_STRIDE];   // 32*100*4 = 12.8 KB

    const int ntiles = batch / TILE;
    for (int tile = blockIdx.x; tile < ntiles; tile += gridDim.x) {
        const f32x4* src = reinterpret_cast<const f32x4*>(x + (size_t)tile * (TILE * IN_CH));
        __syncthreads();                       // protect xs from prior readers
#pragma unroll
        for (int u = 0; u < 2; ++u) {
            const int f4  = t + u * THREADS;   // float4 index 0..767
            const int fl  = f4 * 4;            // flat float index in tile
            const int row = fl / IN_CH;
            const int col = fl % IN_CH;
            const f32x4 v = __builtin_nontemporal_load(&src[f4]);
            *reinterpret_cast<f32x4*>(&xs[row * LDS_STRIDE + col]) = v;
        }
        __syncthreads();

#pragma unroll
        for (int k = 0; k < TILE / 4; ++k) {
            const int r = rl + k * 4;
            const f32x4* xv = reinterpret_cast<const f32x4*>(&xs[r * LDS_STRIDE + c0]);
            const f32x4 xa = xv[0];
            const f32x4 xb = xv[1];
            const f32x4 xc = xv[2];

            f32x4 o4;
#pragma unroll
            for (int j = 0; j < 4; ++j) {
                float acc = b[j];
                acc = fmaf(w[j][0],  xa.x, acc);
                acc = fmaf(w[j][1],  xa.y, acc);
                acc = fmaf(w[j][2],  xa.z, acc);
                acc = fmaf(w[j][3],  xa.w, acc);
                acc = fmaf(w[j][4],  xb.x, acc);
                acc = fmaf(w[j][5],  xb.y, acc);
                acc = fmaf(w[j][6],  xb.z, acc);
                acc = fmaf(w[j][7],  xb.w, acc);
                acc = fmaf(w[j][8],  xc.x, acc);
                acc = fmaf(w[j][9],  xc.y, acc);
                acc = fmaf(w[j][10], xc.z, acc);
                acc = fmaf(w[j][11], xc.w, acc);
                o4[j] = acc;
            }

            f32x4* dst = reinterpret_cast<f32x4*>(
                out + ((size_t)tile * TILE + r) * OUT_CH + chan);
            __builtin_nontemporal_store(o4, dst);   // 16B/lane coalesced
        }
    }
}

extern "C" void kernel_launch(void* const* d_in, const int* in_sizes, int n_in,
                              void* d_out, int out_size, void* d_ws, size_t ws_size,
                              hipStream_t stream) {
    const float* x      = (const float*)d_in[0];
    const float* weight = (const float*)d_in[1];
    const float* mask   = (const float*)d_in[2];
    const float* bias   = (const float*)d_in[3];
    float* out          = (float*)d_out;

    const int batch  = in_sizes[0] / IN_CH;   // 262144
    const int ntiles = batch / TILE;          // 8192
    const int grid   = ntiles < 1280 ? ntiles : 1280;   // grid-stride

    skel_linear_kernel<<<grid, THREADS, 0, stream>>>(x, weight, mask, bias, out, batch);
}

// Round 4
// 114.811 us; speedup vs baseline: 1.1361x; 1.1361x over previous
//
#include <hip/hip_runtime.h>

#define IN_CH 96
#define OUT_CH 384
#define THREADS 384

typedef float f32x4 __attribute__((ext_vector_type(4)));  // native vec for nontemporal builtins

// Barrier-free version: no LDS, no __syncthreads -> no vmcnt(0) drain stalls.
// Thread t handles channel-group cg = t%96 (4 consecutive output channels of
// joint cg>>2) and row lane rl = t/96 (rows 4q+rl). It loads its 12-float
// contiguous x-window directly from global (3x dwordx4; the 3x overlap between
// neighbouring groups is served by L1), does 48 FMAs, and writes one float4.
// Masked weights are hoisted to registers once and reused across ~85 rows.
__global__ __launch_bounds__(THREADS, 5) void skel_linear_kernel(
    const float* __restrict__ x,
    const float* __restrict__ weight,
    const float* __restrict__ mask,
    const float* __restrict__ bias,
    float* __restrict__ out,
    int batch)
{
    const int t     = threadIdx.x;
    const int cg    = t % 96;
    const int rl    = t / 96;          // 0..3
    const int chan  = cg * 4;
    const int joint = cg >> 2;
    const int jc    = (joint - 1 < 0) ? 0 : ((joint - 1 > 21) ? 21 : joint - 1);
    const int c0    = jc * 4;          // contiguous 12-col window [c0, c0+12)

    // Hoist masked weights + bias into registers (once per launch, L2-resident).
    float w[4][12];
    float b[4];
#pragma unroll
    for (int j = 0; j < 4; ++j) {
        const size_t row = (size_t)(chan + j) * IN_CH;
#pragma unroll
        for (int c = 0; c < 12; ++c)
            w[j][c] = weight[row + c0 + c] * mask[row + c0 + c];
        b[j] = bias[chan + j];
    }

    const int nquads = batch >> 2;     // 65536 row-quads
    for (int q = blockIdx.x; q < nquads; q += gridDim.x) {
        const int row = q * 4 + rl;
        const f32x4* xv = reinterpret_cast<const f32x4*>(x + (size_t)row * IN_CH + c0);
        const f32x4 xa = xv[0];
        const f32x4 xb = xv[1];
        const f32x4 xc = xv[2];

        f32x4 o4;
#pragma unroll
        for (int j = 0; j < 4; ++j) {
            float acc = b[j];
            acc = fmaf(w[j][0],  xa.x, acc);
            acc = fmaf(w[j][1],  xa.y, acc);
            acc = fmaf(w[j][2],  xa.z, acc);
            acc = fmaf(w[j][3],  xa.w, acc);
            acc = fmaf(w[j][4],  xb.x, acc);
            acc = fmaf(w[j][5],  xb.y, acc);
            acc = fmaf(w[j][6],  xb.z, acc);
            acc = fmaf(w[j][7],  xb.w, acc);
            acc = fmaf(w[j][8],  xc.x, acc);
            acc = fmaf(w[j][9],  xc.y, acc);
            acc = fmaf(w[j][10], xc.z, acc);
            acc = fmaf(w[j][11], xc.w, acc);
            o4[j] = acc;
        }

        f32x4* dst = reinterpret_cast<f32x4*>(
            out + (size_t)row * OUT_CH + chan);
        __builtin_nontemporal_store(o4, dst);   // 16B/lane, wave covers 1KB contiguous
    }
}

extern "C" void kernel_launch(void* const* d_in, const int* in_sizes, int n_in,
                              void* d_out, int out_size, void* d_ws, size_t ws_size,
                              hipStream_t stream) {
    const float* x      = (const float*)d_in[0];
    const float* weight = (const float*)d_in[1];
    const float* mask   = (const float*)d_in[2];
    const float* bias   = (const float*)d_in[3];
    float* out          = (float*)d_out;

    const int batch = in_sizes[0] / IN_CH;   // 262144
    // 768 = 256 CUs x 3 blocks/CU (6 waves @ <=102 VGPR): all blocks resident,
    // single round, no tail imbalance.
    const int grid = 768;

    skel_linear_kernel<<<grid, THREADS, 0, stream>>>(x, weight, mask, bias, out, batch);
}